// Round 7
// baseline (542.009 us; speedup 1.0000x reference)
//
#include <hip/hip_runtime.h>

#define BATCH 4
#define HH 56
#define WW 56
#define CC 128
#define NHD 4
#define HD 32
#define KS 7
#define NB 3
#define HWSZ (HH * WW)        // 3136
#define RPBW 13
#define QKV_N 384
#define QKV_ELE ((size_t)BATCH * NHD * HWSZ * HD)   // 1,605,632 floats per tensor

// ---------------- Kernel 1: QKV GEMM (exact R3 structure — best measured) ----
// x [12544,128] @ w_qkv[128,384] -> q/k/v each [B,NH,HW,HD], q pre-scaled.
// 64x128 tile / block (588 blocks), 256 threads, 4x8 micro-tile.
__global__ __launch_bounds__(256) void qkv_gemm(
    const float* __restrict__ x, const float* __restrict__ w,
    const float* __restrict__ bias,
    float* __restrict__ qb, float* __restrict__ kb, float* __restrict__ vb)
{
    __shared__ float As[32][68];    // [k][m], 64 rows + pad
    __shared__ float Bs[32][132];   // [k][n]

    const int tid = threadIdx.x;
    const int tx  = tid & 15;
    const int ty  = tid >> 4;       // 0..15 -> rows 4ty..4ty+3
    const int m0  = blockIdx.x * 64;
    const int n0  = blockIdx.y * 128;

    float acc[4][8];
    {
        const float4 ba = *(const float4*)(bias + n0 + 4 * tx);
        const float4 bb = *(const float4*)(bias + n0 + 64 + 4 * tx);
        #pragma unroll
        for (int i = 0; i < 4; ++i) {
            acc[i][0] = ba.x; acc[i][1] = ba.y; acc[i][2] = ba.z; acc[i][3] = ba.w;
            acc[i][4] = bb.x; acc[i][5] = bb.y; acc[i][6] = bb.z; acc[i][7] = bb.w;
        }
    }

    for (int kc = 0; kc < 128; kc += 32) {
        #pragma unroll
        for (int t = tid; t < 512; t += 256) {
            const int row = t >> 3;
            const int k4  = t & 7;
            const float4 xv = *(const float4*)(x + (size_t)(m0 + row) * CC + kc + 4 * k4);
            As[4 * k4 + 0][row] = xv.x;
            As[4 * k4 + 1][row] = xv.y;
            As[4 * k4 + 2][row] = xv.z;
            As[4 * k4 + 3][row] = xv.w;
        }
        #pragma unroll
        for (int t = tid; t < 1024; t += 256) {
            const int kr = t >> 5;
            const int n4 = t & 31;
            *(float4*)&Bs[kr][4 * n4] =
                *(const float4*)(w + (size_t)(kc + kr) * QKV_N + n0 + 4 * n4);
        }
        __syncthreads();
        #pragma unroll
        for (int kk = 0; kk < 32; ++kk) {
            const float4 a0 = *(const float4*)&As[kk][4 * ty];
            const float4 b0 = *(const float4*)&Bs[kk][4 * tx];
            const float4 b1 = *(const float4*)&Bs[kk][64 + 4 * tx];
            const float av[4] = {a0.x, a0.y, a0.z, a0.w};
            const float bv[8] = {b0.x, b0.y, b0.z, b0.w, b1.x, b1.y, b1.z, b1.w};
            #pragma unroll
            for (int i = 0; i < 4; ++i)
                #pragma unroll
                for (int j = 0; j < 8; ++j)
                    acc[i][j] += av[i] * bv[j];
        }
        __syncthreads();
    }

    const int t     = n0 >> 7;   // 0=q 1=k 2=v
    float* dst      = (t == 0) ? qb : (t == 1) ? kb : vb;
    const float scl = (t == 0) ? 0.17677669529663687f : 1.0f;  // 32^-0.5
    const int c0 = 4 * tx;
    const int c1 = 64 + 4 * tx;
    const int h0 = c0 >> 5, d0 = c0 & 31;
    const int h1 = c1 >> 5, d1 = c1 & 31;
    const int b  = m0 / HWSZ;        // 64 | 3136 so tile never crosses b
    #pragma unroll
    for (int i = 0; i < 4; ++i) {
        const int m  = m0 + 4 * ty + i;
        const int ij = m - b * HWSZ;
        float* p0 = dst + ((size_t)(b * NHD + h0) * HWSZ + ij) * HD + d0;
        float* p1 = dst + ((size_t)(b * NHD + h1) * HWSZ + ij) * HD + d1;
        *(float4*)p0 = make_float4(acc[i][0] * scl, acc[i][1] * scl,
                                   acc[i][2] * scl, acc[i][3] * scl);
        *(float4*)p1 = make_float4(acc[i][4] * scl, acc[i][5] * scl,
                                   acc[i][6] * scl, acc[i][7] * scl);
    }
}

// ---------------- Kernel 2: bias init for out ----------------
// out is re-poisoned each iteration; seed with b_proj so attn blocks can
// atomically accumulate their head's projection contribution.
__global__ __launch_bounds__(256) void init_out(
    const float* __restrict__ bias, float4* __restrict__ out4)
{
    const int g = blockIdx.x * 256 + threadIdx.x;   // 401408 float4 total
    const int c4 = g & 31;                          // col/4 within 128
    out4[g] = ((const float4*)bias)[c4];
}

// ---------------- Kernel 3: neighborhood attention + fused projection -------
// Block = 256 threads = 4 waves per (b, head, 8x8 query tile); quad-split
// channels with xor-shuffle reduce (R3-verified). After PV, the 64x32 o-tile
// round-trips through the dead Ks buffer (stride 33: 2-way banks = free) and
// each lane computes out[pixel][sub*32..+31] += o[pixel][:] @ w_proj[head
// slice], accumulated with fp32 atomics (out pre-seeded with b_proj).
__global__ __launch_bounds__(256) void natten_attn_proj(
    const float* __restrict__ qb, const float* __restrict__ kb,
    const float* __restrict__ vb, const float* __restrict__ rpb,
    const float* __restrict__ w_proj, float* __restrict__ out)
{
    __shared__ float4 Ks[8][197];   // [c][pos]; reused as o-tile after scores
    __shared__ float4 Vs[8][197];
    __shared__ float rpbs[RPBW * RPBW];

    const int tid = threadIdx.x;
    const int qid = tid >> 2;       // 0..63 query within 8x8 tile
    const int sub = tid & 3;        // channel-quarter
    const int qi_l = qid >> 3;
    const int qj_l = qid & 7;
    const int ti = blockIdx.x / 7;
    const int tj = blockIdx.x % 7;
    const int head = blockIdx.y;
    const int b    = blockIdx.z;
    const int qi = ti * 8 + qi_l;
    const int qj = tj * 8 + qj_l;
    const int R0 = min(max(ti * 8 - NB, 0), HH - 14);
    const int C0 = min(max(tj * 8 - NB, 0), WW - 14);

    const size_t base = (size_t)(b * NHD + head) * HWSZ;

    if (tid < RPBW * RPBW) rpbs[tid] = rpb[head * (RPBW * RPBW) + tid];

    // stage K+V halo (8 lanes cover one pixel's 128 B -> coalesced)
    for (int idx = tid; idx < 1568; idx += 256) {
        const int pos = idx >> 3;
        const int c   = idx & 7;
        const int ri  = pos / 14;
        const int rj  = pos - ri * 14;
        const size_t g = (base + (size_t)(R0 + ri) * WW + (C0 + rj)) * HD;
        Ks[c][pos] = ((const float4*)(kb + g))[c];
        Vs[c][pos] = ((const float4*)(vb + g))[c];
    }

    // q fragment: my 8 channels (pre-scaled in qkv_gemm)
    const int c0 = sub * 2;
    const float4* qp = (const float4*)(qb + (base + (size_t)qi * WW + qj) * HD) + c0;
    const float4 q0 = qp[0];
    const float4 q1 = qp[1];

    const int si  = min(max(qi - NB, 0), HH - KS);
    const int sj  = min(max(qj - NB, 0), WW - KS);
    const int ri0 = si - R0;
    const int rj0 = sj - C0;
    const int oi  = si - qi + (KS - 1);
    const int oj  = sj - qj + (KS - 1);

    __syncthreads();

    // scores: partial dot over my 8 channels, quad-reduce via shuffles
    float s[49];
    #pragma unroll
    for (int pi = 0; pi < 7; ++pi) {
        const int rowoff = (ri0 + pi) * 14 + rj0;
        const int boff   = (oi + pi) * RPBW + oj;
        #pragma unroll
        for (int pj = 0; pj < 7; ++pj) {
            const int pos = rowoff + pj;
            const float4 k0 = Ks[c0][pos];
            const float4 k1 = Ks[c0 + 1][pos];
            float d = q0.x * k0.x + q0.y * k0.y + q0.z * k0.z + q0.w * k0.w
                    + q1.x * k1.x + q1.y * k1.y + q1.z * k1.z + q1.w * k1.w;
            d += __shfl_xor(d, 1, 64);
            d += __shfl_xor(d, 2, 64);
            s[pi * 7 + pj] = d + rpbs[boff + pj];
        }
    }

    // softmax (replicated across the quad)
    float m = s[0];
    #pragma unroll
    for (int p = 1; p < 49; ++p) m = fmaxf(m, s[p]);
    float l = 0.f;
    #pragma unroll
    for (int p = 0; p < 49; ++p) { s[p] = __expf(s[p] - m); l += s[p]; }
    const float inv = 1.f / l;

    // PV over my 8 channels
    float4 o0 = make_float4(0.f, 0.f, 0.f, 0.f);
    float4 o1 = make_float4(0.f, 0.f, 0.f, 0.f);
    #pragma unroll
    for (int pi = 0; pi < 7; ++pi) {
        const int rowoff = (ri0 + pi) * 14 + rj0;
        #pragma unroll
        for (int pj = 0; pj < 7; ++pj) {
            const int pos = rowoff + pj;
            const float wt = s[pi * 7 + pj];
            const float4 v0 = Vs[c0][pos];
            const float4 v1 = Vs[c0 + 1][pos];
            o0.x += wt * v0.x; o0.y += wt * v0.y; o0.z += wt * v0.z; o0.w += wt * v0.w;
            o1.x += wt * v1.x; o1.y += wt * v1.y; o1.z += wt * v1.z; o1.w += wt * v1.w;
        }
    }

    // ---- fused projection ----
    __syncthreads();               // all waves done with Ks (scores) & Vs (PV)
    float* os = (float*)Ks;        // o-tile: [64 pixels][33] (stride 33 = 2-way banks)
    {
        const int rb = qid * 33 + sub * 8;
        os[rb + 0] = o0.x * inv; os[rb + 1] = o0.y * inv;
        os[rb + 2] = o0.z * inv; os[rb + 3] = o0.w * inv;
        os[rb + 4] = o1.x * inv; os[rb + 5] = o1.y * inv;
        os[rb + 6] = o1.z * inv; os[rb + 7] = o1.w * inv;
    }
    __syncthreads();

    // lane (qid, sub): out[pixel][sub*32 .. +31] += os[qid][:] @ w_proj slice
    float pacc[32];
    #pragma unroll
    for (int j = 0; j < 32; ++j) pacc[j] = 0.f;
    const float* wrow = w_proj + (size_t)(head * HD) * CC + sub * 32;
    const float* orow = os + qid * 33;
    #pragma unroll 4
    for (int c = 0; c < 32; ++c) {
        const float a = orow[c];                 // quad-broadcast, conflict-free
        const float* wr = wrow + (size_t)c * CC; // L1/L2-resident row chunk
        #pragma unroll
        for (int j4 = 0; j4 < 8; ++j4) {
            const float4 wv = *(const float4*)(wr + 4 * j4);
            pacc[4 * j4 + 0] = fmaf(a, wv.x, pacc[4 * j4 + 0]);
            pacc[4 * j4 + 1] = fmaf(a, wv.y, pacc[4 * j4 + 1]);
            pacc[4 * j4 + 2] = fmaf(a, wv.z, pacc[4 * j4 + 2]);
            pacc[4 * j4 + 3] = fmaf(a, wv.w, pacc[4 * j4 + 3]);
        }
    }

    float* op = out + ((size_t)b * HWSZ + (size_t)qi * WW + qj) * CC + sub * 32;
    #pragma unroll
    for (int j = 0; j < 32; ++j) atomicAdd(op + j, pacc[j]);
}

extern "C" void kernel_launch(void* const* d_in, const int* in_sizes, int n_in,
                              void* d_out, int out_size, void* d_ws, size_t ws_size,
                              hipStream_t stream) {
    const float* x      = (const float*)d_in[0];
    const float* w_qkv  = (const float*)d_in[1];
    const float* b_qkv  = (const float*)d_in[2];
    const float* rpb    = (const float*)d_in[3];
    const float* w_proj = (const float*)d_in[4];
    const float* b_proj = (const float*)d_in[5];
    float* out = (float*)d_out;

    float* ws  = (float*)d_ws;
    float* qbf = ws;
    float* kbf = ws + QKV_ELE;
    float* vbf = ws + 2 * QKV_ELE;

    qkv_gemm<<<dim3(196, 3), 256, 0, stream>>>(x, w_qkv, b_qkv, qbf, kbf, vbf);
    init_out<<<1568, 256, 0, stream>>>(b_proj, (float4*)out);
    natten_attn_proj<<<dim3(49, NHD, BATCH), 256, 0, stream>>>(
        qbf, kbf, vbf, rpb, w_proj, out);
}

// Round 8
// 137.337 us; speedup vs baseline: 3.9465x; 3.9465x over previous
//
#include <hip/hip_runtime.h>

#define BATCH 4
#define HH 56
#define WW 56
#define CC 128
#define NHD 4
#define HD 32
#define KS 7
#define NB 3
#define HWSZ (HH * WW)        // 3136
#define RPBW 13
#define QKV_N 384
#define NPIX ((size_t)BATCH * HWSZ)                 // 12544 pixels
#define QKV_ELE ((size_t)BATCH * NHD * HWSZ * HD)   // 1,605,632 floats per tensor

typedef __attribute__((ext_vector_type(8))) short short8;
typedef __attribute__((ext_vector_type(4))) float f32x4;

__device__ __forceinline__ unsigned short f2bf(float f) {
    unsigned u = __float_as_uint(f);
    return (unsigned short)((u + 0x7FFF + ((u >> 16) & 1)) >> 16);
}
__device__ __forceinline__ float bf2f(unsigned short h) {
    return __uint_as_float(((unsigned)h) << 16);
}

// ---------------- Kernel 0: split x into hi/lo bf16; transpose+split weights -
// x[12544][128] -> x_hi/x_lo[12544][128] bf16.
// w_qkv[128][384] -> wt_hi/lo[384][128] bf16 (transposed: MFMA B-frag wants B^T).
// w_proj[128][128] -> wpt_hi/lo[128][128] bf16 (transposed).
__global__ __launch_bounds__(256) void prep_split(
    const float* __restrict__ x, const float* __restrict__ w_qkv,
    const float* __restrict__ w_proj,
    unsigned short* __restrict__ x_hi, unsigned short* __restrict__ x_lo,
    unsigned short* __restrict__ wt_hi, unsigned short* __restrict__ wt_lo,
    unsigned short* __restrict__ wpt_hi, unsigned short* __restrict__ wpt_lo)
{
    const int blk = blockIdx.x;
    if (blk < 1568) {                       // x: 401408 float4 tasks
        const int g = blk * 256 + threadIdx.x;
        const float4 v = ((const float4*)x)[g];
        ushort4 h, l;
        h.x = f2bf(v.x); l.x = f2bf(v.x - bf2f(h.x));
        h.y = f2bf(v.y); l.y = f2bf(v.y - bf2f(h.y));
        h.z = f2bf(v.z); l.z = f2bf(v.z - bf2f(h.z));
        h.w = f2bf(v.w); l.w = f2bf(v.w - bf2f(h.w));
        *(ushort4*)(x_hi + (size_t)g * 4) = h;
        *(ushort4*)(x_lo + (size_t)g * 4) = l;
    } else if (blk < 1760) {                // w_qkv^T: 49152 elements
        const int idx = (blk - 1568) * 256 + threadIdx.x;
        const int n = idx >> 7, k = idx & 127;
        const float v = w_qkv[(size_t)k * QKV_N + n];
        const unsigned short h = f2bf(v);
        wt_hi[idx] = h;
        wt_lo[idx] = f2bf(v - bf2f(h));
    } else {                                // w_proj^T: 16384 elements
        const int idx = (blk - 1760) * 256 + threadIdx.x;
        const int n = idx >> 7, k = idx & 127;
        const float v = w_proj[(size_t)k * CC + n];
        const unsigned short h = f2bf(v);
        wpt_hi[idx] = h;
        wpt_lo[idx] = f2bf(v - bf2f(h));
    }
}

// ---------------- Kernel 1: QKV GEMM via split-bf16 MFMA ----------------
// [12544,128] @ [128,384]: block = 4 waves, one 16-row m-tile; wave wv covers
// n-tiles wv*6..wv*6+5 (all 384 cols per block). Per n-tile: 12 MFMA
// (4 K-chunks x {hh, hl, lh}). Epilogue transposes C via per-wave LDS to
// restore row-major float4 stores into q/k/v [B,NH,HW,HD]; q pre-scaled.
__global__ __launch_bounds__(256) void qkv_mfma(
    const unsigned short* __restrict__ x_hi, const unsigned short* __restrict__ x_lo,
    const unsigned short* __restrict__ wt_hi, const unsigned short* __restrict__ wt_lo,
    const float* __restrict__ bias,
    float* __restrict__ qb, float* __restrict__ kb, float* __restrict__ vb)
{
    __shared__ float tr[4][16][20];     // per-wave transpose pad: 2-way banks (free)

    const int tid  = threadIdx.x;
    const int wv   = tid >> 6;
    const int lane = tid & 63;
    const int ml   = lane & 15;
    const int quad = lane >> 4;
    const int m0   = blockIdx.x * 16;

    // A fragments: A[m=lane&15][k=quad*8+j], row-major x, 4 K-chunks, hi+lo
    short8 a_hi[4], a_lo[4];
    {
        const size_t arow = (size_t)(m0 + ml) * CC;
        #pragma unroll
        for (int c = 0; c < 4; ++c) {
            const int k0 = c * 32 + quad * 8;
            a_hi[c] = *(const short8*)(x_hi + arow + k0);
            a_lo[c] = *(const short8*)(x_lo + arow + k0);
        }
    }

    const int b   = m0 / HWSZ;          // 16 | 3136: tile never crosses batch
    const int ij0 = m0 - b * HWSZ;
    const int row = lane >> 2;          // epilogue: pixel row within tile
    const int c4  = lane & 3;           // epilogue: col quad

    for (int t = 0; t < 6; ++t) {
        const int nt = wv * 6 + t;      // global 16-col tile 0..23
        const int n0 = nt * 16;
        short8 b_hi[4], b_lo[4];
        {
            const size_t brow = (size_t)(n0 + ml) * CC;   // wt is [n][k]
            #pragma unroll
            for (int c = 0; c < 4; ++c) {
                const int k0 = c * 32 + quad * 8;
                b_hi[c] = *(const short8*)(wt_hi + brow + k0);
                b_lo[c] = *(const short8*)(wt_lo + brow + k0);
            }
        }
        f32x4 acc = {0.f, 0.f, 0.f, 0.f};
        #pragma unroll
        for (int c = 0; c < 4; ++c) {
            acc = __builtin_amdgcn_mfma_f32_16x16x32_bf16(a_hi[c], b_hi[c], acc, 0, 0, 0);
            acc = __builtin_amdgcn_mfma_f32_16x16x32_bf16(a_hi[c], b_lo[c], acc, 0, 0, 0);
            acc = __builtin_amdgcn_mfma_f32_16x16x32_bf16(a_lo[c], b_hi[c], acc, 0, 0, 0);
        }

        // C/D: col=lane&15, row=quad*4+reg -> LDS -> row-major float4
        #pragma unroll
        for (int r = 0; r < 4; ++r) tr[wv][quad * 4 + r][ml] = acc[r];
        // per-wave DS ops are in-order; no barrier needed (wave-private region)
        const float4 ov = *(const float4*)&tr[wv][row][c4 * 4];

        const int ten  = nt >> 3;               // 0=q 1=k 2=v
        const int nc   = (nt & 7) * 16;         // col base within tensor
        const int head = nc >> 5;
        const int d0   = (nc & 31) + c4 * 4;
        float* dst      = (ten == 0) ? qb : (ten == 1) ? kb : vb;
        const float scl = (ten == 0) ? 0.17677669529663687f : 1.0f;
        const float4 bv = *(const float4*)(bias + n0 + c4 * 4);
        float* p = dst + ((size_t)(b * NHD + head) * HWSZ + ij0 + row) * HD + d0;
        *(float4*)p = make_float4((ov.x + bv.x) * scl, (ov.y + bv.y) * scl,
                                  (ov.z + bv.z) * scl, (ov.w + bv.w) * scl);
    }
}

// ---------------- Kernel 2: neighborhood attention (R3-verified core) -------
// Block = 256 thr = 4 waves per (b, head, 8x8 query tile); quad-split channels,
// xor-shuffle reduce. Epilogue writes attention output as hi/lo bf16 split
// (proj MFMA input) instead of fp32.
__global__ __launch_bounds__(256) void natten_attn(
    const float* __restrict__ qb, const float* __restrict__ kb,
    const float* __restrict__ vb, const float* __restrict__ rpb,
    unsigned short* __restrict__ o_hi, unsigned short* __restrict__ o_lo)
{
    __shared__ float4 Ks[8][197];   // [c][pos]
    __shared__ float4 Vs[8][197];
    __shared__ float rpbs[RPBW * RPBW];

    const int tid = threadIdx.x;
    const int qid = tid >> 2;       // 0..63 query within 8x8 tile
    const int sub = tid & 3;        // channel-quarter
    const int qi_l = qid >> 3;
    const int qj_l = qid & 7;
    const int ti = blockIdx.x / 7;
    const int tj = blockIdx.x % 7;
    const int head = blockIdx.y;
    const int b    = blockIdx.z;
    const int qi = ti * 8 + qi_l;
    const int qj = tj * 8 + qj_l;
    const int R0 = min(max(ti * 8 - NB, 0), HH - 14);
    const int C0 = min(max(tj * 8 - NB, 0), WW - 14);

    const size_t base = (size_t)(b * NHD + head) * HWSZ;

    if (tid < RPBW * RPBW) rpbs[tid] = rpb[head * (RPBW * RPBW) + tid];

    for (int idx = tid; idx < 1568; idx += 256) {
        const int pos = idx >> 3;
        const int c   = idx & 7;
        const int ri  = pos / 14;
        const int rj  = pos - ri * 14;
        const size_t g = (base + (size_t)(R0 + ri) * WW + (C0 + rj)) * HD;
        Ks[c][pos] = ((const float4*)(kb + g))[c];
        Vs[c][pos] = ((const float4*)(vb + g))[c];
    }

    const int c0 = sub * 2;
    const float4* qp = (const float4*)(qb + (base + (size_t)qi * WW + qj) * HD) + c0;
    const float4 q0 = qp[0];
    const float4 q1 = qp[1];

    const int si  = min(max(qi - NB, 0), HH - KS);
    const int sj  = min(max(qj - NB, 0), WW - KS);
    const int ri0 = si - R0;
    const int rj0 = sj - C0;
    const int oi  = si - qi + (KS - 1);
    const int oj  = sj - qj + (KS - 1);

    __syncthreads();

    float s[49];
    #pragma unroll
    for (int pi = 0; pi < 7; ++pi) {
        const int rowoff = (ri0 + pi) * 14 + rj0;
        const int boff   = (oi + pi) * RPBW + oj;
        #pragma unroll
        for (int pj = 0; pj < 7; ++pj) {
            const int pos = rowoff + pj;
            const float4 k0 = Ks[c0][pos];
            const float4 k1 = Ks[c0 + 1][pos];
            float d = q0.x * k0.x + q0.y * k0.y + q0.z * k0.z + q0.w * k0.w
                    + q1.x * k1.x + q1.y * k1.y + q1.z * k1.z + q1.w * k1.w;
            d += __shfl_xor(d, 1, 64);
            d += __shfl_xor(d, 2, 64);
            s[pi * 7 + pj] = d + rpbs[boff + pj];
        }
    }

    float m = s[0];
    #pragma unroll
    for (int p = 1; p < 49; ++p) m = fmaxf(m, s[p]);
    float l = 0.f;
    #pragma unroll
    for (int p = 0; p < 49; ++p) { s[p] = __expf(s[p] - m); l += s[p]; }
    const float inv = 1.f / l;

    float4 o0 = make_float4(0.f, 0.f, 0.f, 0.f);
    float4 o1 = make_float4(0.f, 0.f, 0.f, 0.f);
    #pragma unroll
    for (int pi = 0; pi < 7; ++pi) {
        const int rowoff = (ri0 + pi) * 14 + rj0;
        #pragma unroll
        for (int pj = 0; pj < 7; ++pj) {
            const int pos = rowoff + pj;
            const float wt = s[pi * 7 + pj];
            const float4 v0 = Vs[c0][pos];
            const float4 v1 = Vs[c0 + 1][pos];
            o0.x += wt * v0.x; o0.y += wt * v0.y; o0.z += wt * v0.z; o0.w += wt * v0.w;
            o1.x += wt * v1.x; o1.y += wt * v1.y; o1.z += wt * v1.z; o1.w += wt * v1.w;
        }
    }

    // epilogue: write hi/lo bf16 split of o*inv into [B,HW,128] layout
    const float vals[8] = {o0.x * inv, o0.y * inv, o0.z * inv, o0.w * inv,
                           o1.x * inv, o1.y * inv, o1.z * inv, o1.w * inv};
    ushort4 h0, h1, l0, l1;
    h0.x = f2bf(vals[0]); l0.x = f2bf(vals[0] - bf2f(h0.x));
    h0.y = f2bf(vals[1]); l0.y = f2bf(vals[1] - bf2f(h0.y));
    h0.z = f2bf(vals[2]); l0.z = f2bf(vals[2] - bf2f(h0.z));
    h0.w = f2bf(vals[3]); l0.w = f2bf(vals[3] - bf2f(h0.w));
    h1.x = f2bf(vals[4]); l1.x = f2bf(vals[4] - bf2f(h1.x));
    h1.y = f2bf(vals[5]); l1.y = f2bf(vals[5] - bf2f(h1.y));
    h1.z = f2bf(vals[6]); l1.z = f2bf(vals[6] - bf2f(h1.z));
    h1.w = f2bf(vals[7]); l1.w = f2bf(vals[7] - bf2f(h1.w));
    const size_t off = ((size_t)b * HWSZ + (size_t)qi * WW + qj) * CC + head * HD + sub * 8;
    *(ushort4*)(o_hi + off)     = h0;
    *(ushort4*)(o_hi + off + 4) = h1;
    *(ushort4*)(o_lo + off)     = l0;
    *(ushort4*)(o_lo + off + 4) = l1;
}

// ---------------- Kernel 3: output projection via split-bf16 MFMA -----------
// [12544,128] @ [128,128] + b_proj. Block = 4 waves on one 16-row m-tile;
// wave wv covers n-tiles wv*2, wv*2+1 (all 128 cols per block).
__global__ __launch_bounds__(256) void proj_mfma(
    const unsigned short* __restrict__ a_hi_g, const unsigned short* __restrict__ a_lo_g,
    const unsigned short* __restrict__ wpt_hi, const unsigned short* __restrict__ wpt_lo,
    const float* __restrict__ bias, float* __restrict__ out)
{
    __shared__ float tr[4][16][20];

    const int tid  = threadIdx.x;
    const int wv   = tid >> 6;
    const int lane = tid & 63;
    const int ml   = lane & 15;
    const int quad = lane >> 4;
    const int m0   = blockIdx.x * 16;

    short8 a_hi[4], a_lo[4];
    {
        const size_t arow = (size_t)(m0 + ml) * CC;
        #pragma unroll
        for (int c = 0; c < 4; ++c) {
            const int k0 = c * 32 + quad * 8;
            a_hi[c] = *(const short8*)(a_hi_g + arow + k0);
            a_lo[c] = *(const short8*)(a_lo_g + arow + k0);
        }
    }

    const int row = lane >> 2;
    const int c4  = lane & 3;

    for (int t = 0; t < 2; ++t) {
        const int nt = wv * 2 + t;      // 0..7
        const int n0 = nt * 16;
        short8 b_hi[4], b_lo[4];
        {
            const size_t brow = (size_t)(n0 + ml) * CC;
            #pragma unroll
            for (int c = 0; c < 4; ++c) {
                const int k0 = c * 32 + quad * 8;
                b_hi[c] = *(const short8*)(wpt_hi + brow + k0);
                b_lo[c] = *(const short8*)(wpt_lo + brow + k0);
            }
        }
        f32x4 acc = {0.f, 0.f, 0.f, 0.f};
        #pragma unroll
        for (int c = 0; c < 4; ++c) {
            acc = __builtin_amdgcn_mfma_f32_16x16x32_bf16(a_hi[c], b_hi[c], acc, 0, 0, 0);
            acc = __builtin_amdgcn_mfma_f32_16x16x32_bf16(a_hi[c], b_lo[c], acc, 0, 0, 0);
            acc = __builtin_amdgcn_mfma_f32_16x16x32_bf16(a_lo[c], b_hi[c], acc, 0, 0, 0);
        }

        #pragma unroll
        for (int r = 0; r < 4; ++r) tr[wv][quad * 4 + r][ml] = acc[r];
        const float4 ov = *(const float4*)&tr[wv][row][c4 * 4];

        const float4 bv = *(const float4*)(bias + n0 + c4 * 4);
        float* p = out + (size_t)(m0 + row) * CC + n0 + c4 * 4;
        *(float4*)p = make_float4(ov.x + bv.x, ov.y + bv.y,
                                  ov.z + bv.z, ov.w + bv.w);
    }
}

extern "C" void kernel_launch(void* const* d_in, const int* in_sizes, int n_in,
                              void* d_out, int out_size, void* d_ws, size_t ws_size,
                              hipStream_t stream) {
    const float* x      = (const float*)d_in[0];
    const float* w_qkv  = (const float*)d_in[1];
    const float* b_qkv  = (const float*)d_in[2];
    const float* rpb    = (const float*)d_in[3];
    const float* w_proj = (const float*)d_in[4];
    const float* b_proj = (const float*)d_in[5];
    float* out = (float*)d_out;

    float* ws = (float*)d_ws;
    float* qbf = ws;                       // QKV_ELE floats each
    float* kbf = ws + QKV_ELE;
    float* vbf = ws + 2 * QKV_ELE;
    size_t off = 3 * QKV_ELE;              // remaining carved as ushort arrays
    const size_t XE = NPIX * CC;           // 1,605,632 ushorts = 802,816 floats
    unsigned short* x_hi  = (unsigned short*)(ws + off); off += XE / 2;
    unsigned short* x_lo  = (unsigned short*)(ws + off); off += XE / 2;
    unsigned short* o_hi  = (unsigned short*)(ws + off); off += XE / 2;
    unsigned short* o_lo  = (unsigned short*)(ws + off); off += XE / 2;
    unsigned short* wt_hi = (unsigned short*)(ws + off); off += 24576;  // 49152 us
    unsigned short* wt_lo = (unsigned short*)(ws + off); off += 24576;
    unsigned short* wpt_hi = (unsigned short*)(ws + off); off += 8192;  // 16384 us
    unsigned short* wpt_lo = (unsigned short*)(ws + off); off += 8192;

    prep_split<<<1824, 256, 0, stream>>>(x, w_qkv, w_proj,
                                         x_hi, x_lo, wt_hi, wt_lo, wpt_hi, wpt_lo);
    qkv_mfma<<<784, 256, 0, stream>>>(x_hi, x_lo, wt_hi, wt_lo, b_qkv,
                                      qbf, kbf, vbf);
    natten_attn<<<dim3(49, NHD, BATCH), 256, 0, stream>>>(qbf, kbf, vbf, rpb,
                                                          o_hi, o_lo);
    proj_mfma<<<784, 256, 0, stream>>>(o_hi, o_lo, wpt_hi, wpt_lo, b_proj, out);
}